// Round 1
// baseline (278.079 us; speedup 1.0000x reference)
//
#include <hip/hip_runtime.h>
#include <hip/hip_bf16.h>

#define B_ 4
#define S_ 512
#define E_ 512
#define U_ 256

// 2*log2(e): pre-scale GEMM outputs so tanh arg feeds exp2 directly:
// exp(2x) = exp2(x * 2*log2(e))
#define KC 2.885390081777927f
#define KLOG2E 1.4426950408889634f

#if __has_builtin(__builtin_amdgcn_exp2f)
#define EXP2F(x) __builtin_amdgcn_exp2f(x)
#else
#define EXP2F(x) __exp2f(x)
#endif

#if __has_builtin(__builtin_amdgcn_rcpf)
#define RCPF(x) __builtin_amdgcn_rcpf(x)
#else
#define RCPF(x) (1.0f / (x))
#endif

// ---------------------------------------------------------------------------
// Kernel A: pre-projections.
//   z==0: keySt[b][u][j] = (h1[b,j,:] @ w1[:,u]) * KC          (transposed!)
//   z==1: qryS [b][i][u] = ((h2[b,i,:] @ w2[:,u]) + b1[u]) * KC
// 64x64 tile per block, 256 threads, 4x4 micro-tile per thread, K-step 16.
// ---------------------------------------------------------------------------
__global__ __launch_bounds__(256) void gemm_pre_kernel(
    const float* __restrict__ h1, const float* __restrict__ h2,
    const float* __restrict__ w, const float* __restrict__ b1,
    float* __restrict__ keySt, float* __restrict__ qryS)
{
    const int z = blockIdx.z;
    const float* __restrict__ A = z ? h2 : h1;
    const float* __restrict__ Bw = w + (z ? (E_ * U_) : 0);

    __shared__ float As[64][17];   // [m][k], +1 pad breaks bank conflicts
    __shared__ float Bs[16][64];   // [k][n]

    const int tid = threadIdx.x;
    const int tm = tid & 15;       // 16 threads over M
    const int tn = tid >> 4;       // 16 threads over N
    const int row0 = blockIdx.x * 64;   // global row (b*S + s)
    const int u0 = blockIdx.y * 64;

    float acc[4][4];
#pragma unroll
    for (int i = 0; i < 4; ++i)
#pragma unroll
        for (int q = 0; q < 4; ++q) acc[i][q] = 0.f;

    for (int k0 = 0; k0 < E_; k0 += 16) {
        // A tile: 64 rows x 16 k — one float4 per thread
        {
            const int m = tid >> 2;
            const int kk = (tid & 3) * 4;
            float4 av = *(const float4*)&A[(size_t)(row0 + m) * E_ + k0 + kk];
            As[m][kk + 0] = av.x; As[m][kk + 1] = av.y;
            As[m][kk + 2] = av.z; As[m][kk + 3] = av.w;
        }
        // B tile: 16 k x 64 n — one float4 per thread, coalesced
        {
            const int kk = tid >> 4;
            const int n4 = (tid & 15) * 4;
            *(float4*)&Bs[kk][n4] =
                *(const float4*)&Bw[(size_t)(k0 + kk) * U_ + u0 + n4];
        }
        __syncthreads();
#pragma unroll
        for (int kk = 0; kk < 16; ++kk) {
            const float a0 = As[tm * 4 + 0][kk];
            const float a1 = As[tm * 4 + 1][kk];
            const float a2 = As[tm * 4 + 2][kk];
            const float a3 = As[tm * 4 + 3][kk];
            const float4 bq = *(const float4*)&Bs[kk][tn * 4];
            acc[0][0] += a0 * bq.x; acc[0][1] += a0 * bq.y;
            acc[0][2] += a0 * bq.z; acc[0][3] += a0 * bq.w;
            acc[1][0] += a1 * bq.x; acc[1][1] += a1 * bq.y;
            acc[1][2] += a1 * bq.z; acc[1][3] += a1 * bq.w;
            acc[2][0] += a2 * bq.x; acc[2][1] += a2 * bq.y;
            acc[2][2] += a2 * bq.z; acc[2][3] += a2 * bq.w;
            acc[3][0] += a3 * bq.x; acc[3][1] += a3 * bq.y;
            acc[3][2] += a3 * bq.z; acc[3][3] += a3 * bq.w;
        }
        __syncthreads();
    }

    const int bb = row0 >> 9;            // row0 / S
    if (z == 0) {
        // transposed store: keySt[b][u][j], 4 consecutive j per float4
        const int j0 = (row0 & (S_ - 1)) + tm * 4;
#pragma unroll
        for (int q = 0; q < 4; ++q) {
            const int u = u0 + tn * 4 + q;
            float4 vv = make_float4(acc[0][q] * KC, acc[1][q] * KC,
                                    acc[2][q] * KC, acc[3][q] * KC);
            *(float4*)&keySt[((size_t)bb * U_ + u) * S_ + j0] = vv;
        }
    } else {
        const float4 bv = *(const float4*)&b1[u0 + tn * 4];
#pragma unroll
        for (int i = 0; i < 4; ++i) {
            const int r = row0 + tm * 4 + i;
            float4 vv = make_float4((acc[i][0] + bv.x) * KC,
                                    (acc[i][1] + bv.y) * KC,
                                    (acc[i][2] + bv.z) * KC,
                                    (acc[i][3] + bv.w) * KC);
            *(float4*)&qryS[(size_t)r * U_ + u0 + tn * 4] = vv;
        }
    }
}

// ---------------------------------------------------------------------------
// Kernel B: fused scores -> softmax -> p @ h1.  One block per (b, i) row.
// 256 threads: thread t owns scores j=2t,2t+1 then output elems e=2t,2t+1.
// b2 dropped (softmax shift-invariant).
// ---------------------------------------------------------------------------
__global__ __launch_bounds__(256) void attend_kernel(
    const float* __restrict__ keySt, const float* __restrict__ qryS,
    const float* __restrict__ v, const float* __restrict__ h1,
    float* __restrict__ out)
{
    const int i = blockIdx.x;
    const int b = blockIdx.y;
    const int t = threadIdx.x;

    __shared__ float sq[U_];
    __shared__ float sv[U_];
    __shared__ float sp[S_];
    __shared__ float sred[8];

    sq[t] = qryS[((size_t)b * S_ + i) * U_ + t];
    sv[t] = v[t];
    __syncthreads();

    // scores: thread t -> j = 2t, 2t+1; loop over u, coalesced keySt reads
    const float* __restrict__ kb = keySt + (size_t)b * U_ * S_;
    const int j2 = 2 * t;
    float acc0 = 0.f, acc1 = 0.f;
#pragma unroll 4
    for (int u = 0; u < U_; ++u) {
        const float2 k2 = *(const float2*)&kb[(size_t)u * S_ + j2];
        const float q = sq[u];
        const float vv = sv[u];
        // args are pre-scaled by 2*log2(e): exp2(a) == exp(2x)
        const float a0 = fminf(q + k2.x, 80.f);   // exp2 underflow (neg) is fine
        const float a1 = fminf(q + k2.y, 80.f);
        const float e0 = EXP2F(a0);
        const float e1 = EXP2F(a1);
        const float t0 = (e0 - 1.f) * RCPF(e0 + 1.f);   // tanh(x)
        const float t1 = (e1 - 1.f) * RCPF(e1 + 1.f);
        acc0 += t0 * vv;
        acc1 += t1 * vv;
    }

    // block softmax over 512 scores
    float m = fmaxf(acc0, acc1);
#pragma unroll
    for (int off = 1; off < 64; off <<= 1)
        m = fmaxf(m, __shfl_xor(m, off, 64));
    if ((t & 63) == 0) sred[t >> 6] = m;
    __syncthreads();
    m = fmaxf(fmaxf(sred[0], sred[1]), fmaxf(sred[2], sred[3]));

    float p0 = EXP2F((acc0 - m) * KLOG2E);
    float p1 = EXP2F((acc1 - m) * KLOG2E);
    float s = p0 + p1;
#pragma unroll
    for (int off = 1; off < 64; off <<= 1)
        s += __shfl_xor(s, off, 64);
    if ((t & 63) == 0) sred[4 + (t >> 6)] = s;   // disjoint from slots 0..3
    __syncthreads();
    s = (sred[4] + sred[5]) + (sred[6] + sred[7]);
    const float rinv = RCPF(s);

    sp[j2] = p0 * rinv;
    sp[j2 + 1] = p1 * rinv;
    __syncthreads();

    // out[b,i,e] = sum_j p[j] * h1[b,j,e]; thread t -> e = 2t, 2t+1
    const float* __restrict__ hb = h1 + (size_t)b * S_ * E_;
    const int e2 = 2 * t;
    float o0 = 0.f, o1 = 0.f;
#pragma unroll 4
    for (int j = 0; j < S_; ++j) {
        const float pj = sp[j];
        const float2 hv = *(const float2*)&hb[(size_t)j * E_ + e2];
        o0 += pj * hv.x;
        o1 += pj * hv.y;
    }
    *(float2*)&out[((size_t)b * S_ + i) * E_ + e2] = make_float2(o0, o1);
}

extern "C" void kernel_launch(void* const* d_in, const int* in_sizes, int n_in,
                              void* d_out, int out_size, void* d_ws, size_t ws_size,
                              hipStream_t stream) {
    const float* h1 = (const float*)d_in[0];
    const float* h2 = (const float*)d_in[1];
    const float* w  = (const float*)d_in[2];
    const float* b1 = (const float*)d_in[3];
    const float* v  = (const float*)d_in[4];
    // d_in[5] = b2: cancels in softmax, unused.
    float* out = (float*)d_out;

    float* keySt = (float*)d_ws;                          // B*U*S floats (2 MB)
    float* qryS  = keySt + (size_t)B_ * U_ * S_;          // B*S*U floats (2 MB)

    dim3 g1(B_ * S_ / 64, U_ / 64, 2);
    gemm_pre_kernel<<<g1, dim3(256), 0, stream>>>(h1, h2, w, b1, keySt, qryS);

    dim3 g2(S_, B_);
    attend_kernel<<<g2, dim3(256), 0, stream>>>(keySt, qryS, v, h1, out);
}

// Round 2
// 196.809 us; speedup vs baseline: 1.4129x; 1.4129x over previous
//
#include <hip/hip_runtime.h>
#include <hip/hip_bf16.h>

#define B_ 4
#define S_ 512
#define E_ 512
#define U_ 256
#define TI 4   // query rows per attend block

// 2*log2(e): pre-scale GEMM outputs so tanh arg feeds exp2 directly:
// exp(2x) = exp2(x * 2*log2(e))
#define KC 2.885390081777927f
#define KLOG2E 1.4426950408889634f

#if __has_builtin(__builtin_amdgcn_exp2f)
#define EXP2F(x) __builtin_amdgcn_exp2f(x)
#else
#define EXP2F(x) __exp2f(x)
#endif

#if __has_builtin(__builtin_amdgcn_rcpf)
#define RCPF(x) __builtin_amdgcn_rcpf(x)
#else
#define RCPF(x) (1.0f / (x))
#endif

// ---------------------------------------------------------------------------
// Kernel A: pre-projections.  32x64 tile, 256 threads, 2x4 micro-tile.
//   z==0: keySt[b][u][j] = (h1[b,j,:] @ w1[:,u]) * KC          (transposed!)
//   z==1: qryS [b][i][u] = ((h2[b,i,:] @ w2[:,u]) + b1[u]) * KC
// grid (64, 4, 2) = 512 blocks -> 2 blocks/CU, 8 waves/CU.
// ---------------------------------------------------------------------------
__global__ __launch_bounds__(256) void gemm_pre_kernel(
    const float* __restrict__ h1, const float* __restrict__ h2,
    const float* __restrict__ w, const float* __restrict__ b1,
    float* __restrict__ keySt, float* __restrict__ qryS)
{
    const int z = blockIdx.z;
    const float* __restrict__ A = z ? h2 : h1;
    const float* __restrict__ Bw = w + (z ? (E_ * U_) : 0);

    __shared__ float As[16][34];   // [k][m], stride 34 keeps 8B align + no 2^k stride
    __shared__ float Bs[16][64];   // [k][n]

    const int tid = threadIdx.x;
    const int tm = tid & 15;       // 16 threads over M (x2 rows each)
    const int tn = tid >> 4;       // 16 threads over N (x4 cols each)
    const int row0 = blockIdx.x * 32;   // global row (b*S + s)
    const int u0 = blockIdx.y * 64;

    // A-load indices: 32 rows x 16 k, one float2 per thread
    const int am = tid >> 3;
    const int ak = (tid & 7) * 2;
    // B-load indices: 16 k x 64 n, one float4 per thread
    const int bk = tid >> 4;
    const int bn = (tid & 15) * 4;

    float acc[2][4];
#pragma unroll
    for (int i = 0; i < 2; ++i)
#pragma unroll
        for (int q = 0; q < 4; ++q) acc[i][q] = 0.f;

    for (int k0 = 0; k0 < E_; k0 += 16) {
        float2 av = *(const float2*)&A[(size_t)(row0 + am) * E_ + k0 + ak];
        float4 bv = *(const float4*)&Bw[(size_t)(k0 + bk) * U_ + u0 + bn];
        As[ak][am] = av.x;
        As[ak + 1][am] = av.y;
        *(float4*)&Bs[bk][bn] = bv;
        __syncthreads();
#pragma unroll
        for (int kk = 0; kk < 16; ++kk) {
            const float2 a2 = *(const float2*)&As[kk][tm * 2];
            const float4 bq = *(const float4*)&Bs[kk][tn * 4];
            acc[0][0] += a2.x * bq.x; acc[0][1] += a2.x * bq.y;
            acc[0][2] += a2.x * bq.z; acc[0][3] += a2.x * bq.w;
            acc[1][0] += a2.y * bq.x; acc[1][1] += a2.y * bq.y;
            acc[1][2] += a2.y * bq.z; acc[1][3] += a2.y * bq.w;
        }
        __syncthreads();
    }

    const int bb = row0 >> 9;            // row0 / S
    if (z == 0) {
        // transposed store: keySt[b][u][j]
        const int j0 = (row0 & (S_ - 1)) + tm * 2;
#pragma unroll
        for (int q = 0; q < 4; ++q) {
            const int u = u0 + tn * 4 + q;
            float2 vv = make_float2(acc[0][q] * KC, acc[1][q] * KC);
            *(float2*)&keySt[((size_t)bb * U_ + u) * S_ + j0] = vv;
        }
    } else {
        const float4 bvq = *(const float4*)&b1[u0 + tn * 4];
#pragma unroll
        for (int i = 0; i < 2; ++i) {
            const int r = row0 + tm * 2 + i;
            float4 vv = make_float4((acc[i][0] + bvq.x) * KC,
                                    (acc[i][1] + bvq.y) * KC,
                                    (acc[i][2] + bvq.z) * KC,
                                    (acc[i][3] + bvq.w) * KC);
            *(float4*)&qryS[(size_t)r * U_ + u0 + tn * 4] = vv;
        }
    }
}

// ---------------------------------------------------------------------------
// Kernel B: fused scores -> softmax -> p @ h1.  One block per (b, 4 rows i).
// 256 threads: thread t owns j = 2t,2t+1 for all 4 rows, then e = 2t,2t+1.
// Identity used: sum_u v_u*tanh(x_u) = const - sum_u 2*v_u*rcp(exp(2x_u)+1);
// the const (and b2) cancel in softmax. Inner element = add,exp2,add,rcp,fma.
// ---------------------------------------------------------------------------
__global__ __launch_bounds__(256) void attend_kernel(
    const float* __restrict__ keySt, const float* __restrict__ qryS,
    const float* __restrict__ v, const float* __restrict__ h1,
    float* __restrict__ out)
{
    const int i0 = blockIdx.x * TI;
    const int b = blockIdx.y;
    const int t = threadIdx.x;

    __shared__ float sqT[U_][TI];    // q transposed: [u][i] -> one b128 per u
    __shared__ float sv2[U_];        // -2*v[u]
    __shared__ float spT[S_][TI];    // p transposed: [j][i] -> one b128 per j
    __shared__ float smx[4][TI];
    __shared__ float ssm[4][TI];

#pragma unroll
    for (int i = 0; i < TI; ++i)
        sqT[t][i] = qryS[((size_t)b * S_ + i0 + i) * U_ + t];
    sv2[t] = -2.f * v[t];
    __syncthreads();

    // ---- phase 1: shifted scores acc[i][jj] for j = 2t, 2t+1 ----
    const float2* __restrict__ kb2 =
        (const float2*)(keySt + (size_t)b * U_ * S_) + t;
    float a00 = 0.f, a01 = 0.f, a10 = 0.f, a11 = 0.f;
    float a20 = 0.f, a21 = 0.f, a30 = 0.f, a31 = 0.f;
#pragma unroll 2
    for (int u = 0; u < U_; ++u) {
        const float2 k2 = kb2[u * (S_ / 2)];
        const float4 q = *(const float4*)&sqT[u][0];
        const float vv = sv2[u];
        // all args pre-scaled by 2*log2(e): exp2(arg) == exp(2x)
        const float r00 = RCPF(EXP2F(q.x + k2.x) + 1.f);
        const float r01 = RCPF(EXP2F(q.x + k2.y) + 1.f);
        const float r10 = RCPF(EXP2F(q.y + k2.x) + 1.f);
        const float r11 = RCPF(EXP2F(q.y + k2.y) + 1.f);
        const float r20 = RCPF(EXP2F(q.z + k2.x) + 1.f);
        const float r21 = RCPF(EXP2F(q.z + k2.y) + 1.f);
        const float r30 = RCPF(EXP2F(q.w + k2.x) + 1.f);
        const float r31 = RCPF(EXP2F(q.w + k2.y) + 1.f);
        a00 += vv * r00; a01 += vv * r01;
        a10 += vv * r10; a11 += vv * r11;
        a20 += vv * r20; a21 += vv * r21;
        a30 += vv * r30; a31 += vv * r31;
    }

    // ---- softmax over j per row i (4 rows at once) ----
    float m0 = fmaxf(a00, a01), m1 = fmaxf(a10, a11);
    float m2 = fmaxf(a20, a21), m3 = fmaxf(a30, a31);
#pragma unroll
    for (int off = 1; off < 64; off <<= 1) {
        m0 = fmaxf(m0, __shfl_xor(m0, off, 64));
        m1 = fmaxf(m1, __shfl_xor(m1, off, 64));
        m2 = fmaxf(m2, __shfl_xor(m2, off, 64));
        m3 = fmaxf(m3, __shfl_xor(m3, off, 64));
    }
    const int wv = t >> 6;
    if ((t & 63) == 0) { smx[wv][0] = m0; smx[wv][1] = m1; smx[wv][2] = m2; smx[wv][3] = m3; }
    __syncthreads();
    m0 = fmaxf(fmaxf(smx[0][0], smx[1][0]), fmaxf(smx[2][0], smx[3][0]));
    m1 = fmaxf(fmaxf(smx[0][1], smx[1][1]), fmaxf(smx[2][1], smx[3][1]));
    m2 = fmaxf(fmaxf(smx[0][2], smx[1][2]), fmaxf(smx[2][2], smx[3][2]));
    m3 = fmaxf(fmaxf(smx[0][3], smx[1][3]), fmaxf(smx[2][3], smx[3][3]));

    const float p00 = EXP2F((a00 - m0) * KLOG2E), p01 = EXP2F((a01 - m0) * KLOG2E);
    const float p10 = EXP2F((a10 - m1) * KLOG2E), p11 = EXP2F((a11 - m1) * KLOG2E);
    const float p20 = EXP2F((a20 - m2) * KLOG2E), p21 = EXP2F((a21 - m2) * KLOG2E);
    const float p30 = EXP2F((a30 - m3) * KLOG2E), p31 = EXP2F((a31 - m3) * KLOG2E);
    float s0 = p00 + p01, s1 = p10 + p11, s2 = p20 + p21, s3 = p30 + p31;
#pragma unroll
    for (int off = 1; off < 64; off <<= 1) {
        s0 += __shfl_xor(s0, off, 64);
        s1 += __shfl_xor(s1, off, 64);
        s2 += __shfl_xor(s2, off, 64);
        s3 += __shfl_xor(s3, off, 64);
    }
    if ((t & 63) == 0) { ssm[wv][0] = s0; ssm[wv][1] = s1; ssm[wv][2] = s2; ssm[wv][3] = s3; }
    __syncthreads();
    s0 = (ssm[0][0] + ssm[1][0]) + (ssm[2][0] + ssm[3][0]);
    s1 = (ssm[0][1] + ssm[1][1]) + (ssm[2][1] + ssm[3][1]);
    s2 = (ssm[0][2] + ssm[1][2]) + (ssm[2][2] + ssm[3][2]);
    s3 = (ssm[0][3] + ssm[1][3]) + (ssm[2][3] + ssm[3][3]);
    const float r0 = RCPF(s0), r1 = RCPF(s1), r2 = RCPF(s2), r3 = RCPF(s3);

    const int j2 = 2 * t;
    spT[j2][0] = p00 * r0; spT[j2][1] = p10 * r1;
    spT[j2][2] = p20 * r2; spT[j2][3] = p30 * r3;
    spT[j2 + 1][0] = p01 * r0; spT[j2 + 1][1] = p11 * r1;
    spT[j2 + 1][2] = p21 * r2; spT[j2 + 1][3] = p31 * r3;
    __syncthreads();

    // ---- phase 2: out[b, i0+i, e] = sum_j p[i][j] * h1[b,j,e] ----
    const float* __restrict__ hb = h1 + (size_t)b * S_ * E_;
    const int e2 = 2 * t;
    float o00 = 0.f, o01 = 0.f, o10 = 0.f, o11 = 0.f;
    float o20 = 0.f, o21 = 0.f, o30 = 0.f, o31 = 0.f;
#pragma unroll 4
    for (int j = 0; j < S_; ++j) {
        const float2 hv = *(const float2*)&hb[(size_t)j * E_ + e2];
        const float4 pj = *(const float4*)&spT[j][0];
        o00 += pj.x * hv.x; o01 += pj.x * hv.y;
        o10 += pj.y * hv.x; o11 += pj.y * hv.y;
        o20 += pj.z * hv.x; o21 += pj.z * hv.y;
        o30 += pj.w * hv.x; o31 += pj.w * hv.y;
    }
    float* ob = out + ((size_t)b * S_ + i0) * E_ + e2;
    *(float2*)&ob[0 * E_] = make_float2(o00, o01);
    *(float2*)&ob[1 * E_] = make_float2(o10, o11);
    *(float2*)&ob[2 * E_] = make_float2(o20, o21);
    *(float2*)&ob[3 * E_] = make_float2(o30, o31);
}

extern "C" void kernel_launch(void* const* d_in, const int* in_sizes, int n_in,
                              void* d_out, int out_size, void* d_ws, size_t ws_size,
                              hipStream_t stream) {
    const float* h1 = (const float*)d_in[0];
    const float* h2 = (const float*)d_in[1];
    const float* w  = (const float*)d_in[2];
    const float* b1 = (const float*)d_in[3];
    const float* v  = (const float*)d_in[4];
    // d_in[5] = b2: cancels in softmax, unused.
    float* out = (float*)d_out;

    float* keySt = (float*)d_ws;                          // B*U*S floats (2 MB)
    float* qryS  = keySt + (size_t)B_ * U_ * S_;          // B*S*U floats (2 MB)

    dim3 g1(B_ * S_ / 32, U_ / 64, 2);
    gemm_pre_kernel<<<g1, dim3(256), 0, stream>>>(h1, h2, w, b1, keySt, qryS);

    dim3 g2(S_ / TI, B_);
    attend_kernel<<<g2, dim3(256), 0, stream>>>(keySt, qryS, v, h1, out);
}

// Round 3
// 186.699 us; speedup vs baseline: 1.4895x; 1.0542x over previous
//
#include <hip/hip_runtime.h>
#include <hip/hip_bf16.h>

#define B_ 4
#define S_ 512
#define E_ 512
#define U_ 256

// 2*log2(e): fold into w so tanh arg feeds exp2 directly: exp(2x) = exp2(KC*x)
#define KC 2.885390081777927f
#define KLOG2E 1.4426950408889634f

#if __has_builtin(__builtin_amdgcn_exp2f)
#define EXP2F(x) __builtin_amdgcn_exp2f(x)
#else
#define EXP2F(x) __exp2f(x)
#endif

#if __has_builtin(__builtin_amdgcn_rcpf)
#define RCPF(x) __builtin_amdgcn_rcpf(x)
#else
#define RCPF(x) (1.0f / (x))
#endif

// ---------------------------------------------------------------------------
// Kernel 1: pre-projections. 64x64 tile, 256 thr, 4x4 micro, K-step 32.
// grid (32, 4, 2) = 256 blocks (1/CU). A,B staged in LDS k-major -> all frag
// reads are b128. w scaled by KC at staging; b1 folded later in scores.
//   z==0: keySt[b][u][j] = KC * (h1[b,j,:] @ w1[:,u])     (transposed)
//   z==1: qryS [b][i][u] = KC * (h2[b,i,:] @ w2[:,u])
// ---------------------------------------------------------------------------
__global__ __launch_bounds__(256) void gemm_pre(
    const float* __restrict__ h1, const float* __restrict__ h2,
    const float* __restrict__ w,
    float* __restrict__ keySt, float* __restrict__ qryS)
{
    const int z = blockIdx.z;
    const float* __restrict__ A = z ? h2 : h1;
    const float* __restrict__ Bw = w + (z ? (E_ * U_) : 0);

    __shared__ float As[32][65];   // [k][m], stride 65 de-conflicts transpose stores
    __shared__ float Bs[32][64];   // [k][n]

    const int tid = threadIdx.x;
    const int tm = tid & 15;       // m-group: rows tm*4..+3
    const int tn = tid >> 4;       // n-group: cols tn*4..+3
    const int row0 = blockIdx.x * 64;   // global row in 0..2047 (= b*S + s)
    const int u0 = blockIdx.y * 64;

    // staging indices
    const int ar = tid >> 3;            // A rows 0..31 (and +32)
    const int ak = (tid & 7) * 4;       // A k-offset
    const int bk = tid >> 4;            // B k 0..15 (and +16)
    const int bn = (tid & 15) * 4;      // B n-offset

    float acc[4][4];
#pragma unroll
    for (int i = 0; i < 4; ++i)
#pragma unroll
        for (int q = 0; q < 4; ++q) acc[i][q] = 0.f;

    for (int k0 = 0; k0 < E_; k0 += 32) {
        const float4 a0 = *(const float4*)&A[(size_t)(row0 + ar) * E_ + k0 + ak];
        const float4 a1 = *(const float4*)&A[(size_t)(row0 + 32 + ar) * E_ + k0 + ak];
        float4 b0 = *(const float4*)&Bw[(size_t)(k0 + bk) * U_ + u0 + bn];
        float4 b1v = *(const float4*)&Bw[(size_t)(k0 + 16 + bk) * U_ + u0 + bn];
        b0.x *= KC; b0.y *= KC; b0.z *= KC; b0.w *= KC;
        b1v.x *= KC; b1v.y *= KC; b1v.z *= KC; b1v.w *= KC;
        __syncthreads();
        As[ak + 0][ar] = a0.x; As[ak + 1][ar] = a0.y;
        As[ak + 2][ar] = a0.z; As[ak + 3][ar] = a0.w;
        As[ak + 0][32 + ar] = a1.x; As[ak + 1][32 + ar] = a1.y;
        As[ak + 2][32 + ar] = a1.z; As[ak + 3][32 + ar] = a1.w;
        *(float4*)&Bs[bk][bn] = b0;
        *(float4*)&Bs[16 + bk][bn] = b1v;
        __syncthreads();
#pragma unroll
        for (int kk = 0; kk < 32; ++kk) {
            const float4 a4 = *(const float4*)&As[kk][tm * 4];
            const float4 b4 = *(const float4*)&Bs[kk][tn * 4];
            acc[0][0] += a4.x * b4.x; acc[0][1] += a4.x * b4.y;
            acc[0][2] += a4.x * b4.z; acc[0][3] += a4.x * b4.w;
            acc[1][0] += a4.y * b4.x; acc[1][1] += a4.y * b4.y;
            acc[1][2] += a4.y * b4.z; acc[1][3] += a4.y * b4.w;
            acc[2][0] += a4.z * b4.x; acc[2][1] += a4.z * b4.y;
            acc[2][2] += a4.z * b4.z; acc[2][3] += a4.z * b4.w;
            acc[3][0] += a4.w * b4.x; acc[3][1] += a4.w * b4.y;
            acc[3][2] += a4.w * b4.z; acc[3][3] += a4.w * b4.w;
        }
    }

    if (z == 0) {
        const int bb = row0 >> 9;
        const int j0 = (row0 & (S_ - 1)) + tm * 4;
#pragma unroll
        for (int c = 0; c < 4; ++c) {
            const int u = u0 + tn * 4 + c;
            float4 vv = make_float4(acc[0][c], acc[1][c], acc[2][c], acc[3][c]);
            *(float4*)&keySt[((size_t)bb * U_ + u) * S_ + j0] = vv;
        }
    } else {
#pragma unroll
        for (int r = 0; r < 4; ++r) {
            const int row = row0 + tm * 4 + r;
            *(float4*)&qryS[(size_t)row * U_ + u0 + tn * 4] =
                make_float4(acc[r][0], acc[r][1], acc[r][2], acc[r][3]);
        }
    }
}

// ---------------------------------------------------------------------------
// Kernel 2: scores + softmax -> normalized P.  One block per (b, 2 rows).
// grid (256, 4) = 1024 blocks -> 4 blocks/CU, 16 waves/CU.
// Identity: sum_u v_u*tanh(x) = const - sum_u 2*v_u/(exp(2x)+1); const and b2
// cancel in softmax. No clamp needed: exp2->inf => rcp->0 (tanh->1 limit).
// ---------------------------------------------------------------------------
__global__ __launch_bounds__(256) void scores_kernel(
    const float* __restrict__ keySt, const float* __restrict__ qryS,
    const float* __restrict__ b1, const float* __restrict__ v,
    float* __restrict__ P)
{
    const int i0 = blockIdx.x * 2;
    const int b = blockIdx.y;
    const int t = threadIdx.x;

    __shared__ float sq0[U_], sq1[U_], sv2[U_];
    __shared__ float smx[4][2], ssm[4][2];

    const float kb1 = KC * b1[t];
    sq0[t] = qryS[((size_t)b * S_ + i0) * U_ + t] + kb1;
    sq1[t] = qryS[((size_t)b * S_ + i0 + 1) * U_ + t] + kb1;
    sv2[t] = -2.f * v[t];
    __syncthreads();

    const float2* __restrict__ kb2 =
        (const float2*)(keySt + (size_t)b * U_ * S_) + t;
    float a00 = 0.f, a01 = 0.f, a10 = 0.f, a11 = 0.f;
#pragma unroll 4
    for (int u = 0; u < U_; ++u) {
        const float2 k2 = kb2[u * (S_ / 2)];
        const float q0 = sq0[u], q1 = sq1[u], vv = sv2[u];
        const float r00 = RCPF(EXP2F(q0 + k2.x) + 1.f);
        const float r01 = RCPF(EXP2F(q0 + k2.y) + 1.f);
        const float r10 = RCPF(EXP2F(q1 + k2.x) + 1.f);
        const float r11 = RCPF(EXP2F(q1 + k2.y) + 1.f);
        a00 += vv * r00; a01 += vv * r01;
        a10 += vv * r10; a11 += vv * r11;
    }

    float m0 = fmaxf(a00, a01), m1 = fmaxf(a10, a11);
#pragma unroll
    for (int off = 1; off < 64; off <<= 1) {
        m0 = fmaxf(m0, __shfl_xor(m0, off, 64));
        m1 = fmaxf(m1, __shfl_xor(m1, off, 64));
    }
    const int wv = t >> 6;
    if ((t & 63) == 0) { smx[wv][0] = m0; smx[wv][1] = m1; }
    __syncthreads();
    m0 = fmaxf(fmaxf(smx[0][0], smx[1][0]), fmaxf(smx[2][0], smx[3][0]));
    m1 = fmaxf(fmaxf(smx[0][1], smx[1][1]), fmaxf(smx[2][1], smx[3][1]));

    const float p00 = EXP2F((a00 - m0) * KLOG2E), p01 = EXP2F((a01 - m0) * KLOG2E);
    const float p10 = EXP2F((a10 - m1) * KLOG2E), p11 = EXP2F((a11 - m1) * KLOG2E);
    float s0 = p00 + p01, s1 = p10 + p11;
#pragma unroll
    for (int off = 1; off < 64; off <<= 1) {
        s0 += __shfl_xor(s0, off, 64);
        s1 += __shfl_xor(s1, off, 64);
    }
    if ((t & 63) == 0) { ssm[wv][0] = s0; ssm[wv][1] = s1; }
    __syncthreads();
    s0 = (ssm[0][0] + ssm[1][0]) + (ssm[2][0] + ssm[3][0]);
    s1 = (ssm[0][1] + ssm[1][1]) + (ssm[2][1] + ssm[3][1]);
    const float r0 = RCPF(s0), r1 = RCPF(s1);

    float* __restrict__ prow = P + ((size_t)b * S_ + i0) * S_ + 2 * t;
    *(float2*)prow = make_float2(p00 * r0, p01 * r0);
    *(float2*)(prow + S_) = make_float2(p10 * r1, p11 * r1);
}

// ---------------------------------------------------------------------------
// Kernel 3: out[b] = P[b] @ h1[b].  Same tiling as gemm_pre.
// grid (8, 8, 4) = 256 blocks (1/CU). M=i, N=e, K=j (512).
// ---------------------------------------------------------------------------
__global__ __launch_bounds__(256) void pv_gemm(
    const float* __restrict__ P, const float* __restrict__ h1,
    float* __restrict__ out)
{
    const int b = blockIdx.z;
    const float* __restrict__ A = P + (size_t)b * S_ * S_;
    const float* __restrict__ Bh = h1 + (size_t)b * S_ * E_;

    __shared__ float As[32][65];
    __shared__ float Bs[32][64];

    const int tid = threadIdx.x;
    const int tm = tid & 15;
    const int tn = tid >> 4;
    const int i0 = blockIdx.x * 64;
    const int e0 = blockIdx.y * 64;

    const int ar = tid >> 3;
    const int ak = (tid & 7) * 4;
    const int bk = tid >> 4;
    const int bn = (tid & 15) * 4;

    float acc[4][4];
#pragma unroll
    for (int i = 0; i < 4; ++i)
#pragma unroll
        for (int q = 0; q < 4; ++q) acc[i][q] = 0.f;

    for (int k0 = 0; k0 < S_; k0 += 32) {
        const float4 a0 = *(const float4*)&A[(size_t)(i0 + ar) * S_ + k0 + ak];
        const float4 a1 = *(const float4*)&A[(size_t)(i0 + 32 + ar) * S_ + k0 + ak];
        const float4 b0 = *(const float4*)&Bh[(size_t)(k0 + bk) * E_ + e0 + bn];
        const float4 b1v = *(const float4*)&Bh[(size_t)(k0 + 16 + bk) * E_ + e0 + bn];
        __syncthreads();
        As[ak + 0][ar] = a0.x; As[ak + 1][ar] = a0.y;
        As[ak + 2][ar] = a0.z; As[ak + 3][ar] = a0.w;
        As[ak + 0][32 + ar] = a1.x; As[ak + 1][32 + ar] = a1.y;
        As[ak + 2][32 + ar] = a1.z; As[ak + 3][32 + ar] = a1.w;
        *(float4*)&Bs[bk][bn] = b0;
        *(float4*)&Bs[16 + bk][bn] = b1v;
        __syncthreads();
#pragma unroll
        for (int kk = 0; kk < 32; ++kk) {
            const float4 a4 = *(const float4*)&As[kk][tm * 4];
            const float4 b4 = *(const float4*)&Bs[kk][tn * 4];
            acc[0][0] += a4.x * b4.x; acc[0][1] += a4.x * b4.y;
            acc[0][2] += a4.x * b4.z; acc[0][3] += a4.x * b4.w;
            acc[1][0] += a4.y * b4.x; acc[1][1] += a4.y * b4.y;
            acc[1][2] += a4.y * b4.z; acc[1][3] += a4.y * b4.w;
            acc[2][0] += a4.z * b4.x; acc[2][1] += a4.z * b4.y;
            acc[2][2] += a4.z * b4.z; acc[2][3] += a4.z * b4.w;
            acc[3][0] += a4.w * b4.x; acc[3][1] += a4.w * b4.y;
            acc[3][2] += a4.w * b4.z; acc[3][3] += a4.w * b4.w;
        }
    }

#pragma unroll
    for (int r = 0; r < 4; ++r) {
        const int row = i0 + tm * 4 + r;
        *(float4*)&out[((size_t)b * S_ + row) * E_ + e0 + tn * 4] =
            make_float4(acc[r][0], acc[r][1], acc[r][2], acc[r][3]);
    }
}

extern "C" void kernel_launch(void* const* d_in, const int* in_sizes, int n_in,
                              void* d_out, int out_size, void* d_ws, size_t ws_size,
                              hipStream_t stream) {
    const float* h1 = (const float*)d_in[0];
    const float* h2 = (const float*)d_in[1];
    const float* w  = (const float*)d_in[2];
    const float* b1 = (const float*)d_in[3];
    const float* v  = (const float*)d_in[4];
    // d_in[5] = b2: cancels in softmax, unused.
    float* out = (float*)d_out;

    float* keySt = (float*)d_ws;                           // 2 MB
    float* qryS  = keySt + (size_t)B_ * U_ * S_;           // 2 MB
    float* P     = qryS + (size_t)B_ * S_ * U_;            // 4 MB

    dim3 g1(32, 4, 2);
    gemm_pre<<<g1, dim3(256), 0, stream>>>(h1, h2, w, keySt, qryS);

    dim3 g2(S_ / 2, B_);
    scores_kernel<<<g2, dim3(256), 0, stream>>>(keySt, qryS, b1, v, P);

    dim3 g3(S_ / 64, E_ / 64, B_);
    pv_gemm<<<g3, dim3(256), 0, stream>>>(P, h1, out);
}